// Round 3
// baseline (1885.739 us; speedup 1.0000x reference)
//
#include <hip/hip_runtime.h>

#define NN 50000
#define NE 800000
#define NL 12
#define DD 64

__device__ __forceinline__ float rl(float v, int k) {
    return __int_as_float(__builtin_amdgcn_readlane(__float_as_int(v), k));
}

// ---------------------------------------------------------------------------
// Detect whether edge_index is stored as int64 (odd 32-bit words all zero).
// ---------------------------------------------------------------------------
__global__ __launch_bounds__(256) void detect_i64(const unsigned int* __restrict__ w,
                                                  int* __restrict__ flag) {
    __shared__ unsigned int red[256];
    unsigned int v = 0;
    for (int i = threadIdx.x; i < 4096; i += 256) v |= w[2 * i + 1];
    red[threadIdx.x] = v;
    __syncthreads();
    for (int s = 128; s > 0; s >>= 1) {
        if (threadIdx.x < s) red[threadIdx.x] |= red[threadIdx.x + s];
        __syncthreads();
    }
    if (threadIdx.x == 0) *flag = (red[0] == 0u) ? 1 : 0;
}

__global__ __launch_bounds__(256) void hist_k(const void* __restrict__ eidx,
                                              const int* __restrict__ flag,
                                              int* __restrict__ cnt) {
    int e = blockIdx.x * 256 + threadIdx.x;
    if (e >= NE) return;
    int dst;
    if (*flag) dst = (int)((const long long*)eidx)[NE + e];
    else       dst = ((const int*)eidx)[NE + e];
    atomicAdd(&cnt[dst], 1);
}

__global__ __launch_bounds__(1024) void scan_k(const int* __restrict__ cnt,
                                               int* __restrict__ offs,
                                               int* __restrict__ cursor) {
    __shared__ int wsum[16];
    __shared__ int carry_s;
    int tid = threadIdx.x;
    int lane = tid & 63;
    int wv = tid >> 6;
    if (tid == 0) carry_s = 0;
    __syncthreads();
    for (int base = 0; base < NN; base += 1024) {
        int i = base + tid;
        int v = (i < NN) ? cnt[i] : 0;
        int incl = v;
        #pragma unroll
        for (int d = 1; d < 64; d <<= 1) {
            int t = __shfl_up(incl, d);
            if (lane >= d) incl += t;
        }
        if (lane == 63) wsum[wv] = incl;
        __syncthreads();
        if (wv == 0) {
            int s = (lane < 16) ? wsum[lane] : 0;
            #pragma unroll
            for (int d = 1; d < 16; d <<= 1) {
                int t = __shfl_up(s, d);
                if (lane >= d) s += t;
            }
            if (lane < 16) wsum[lane] = s;
        }
        __syncthreads();
        int wbase = (wv == 0) ? 0 : wsum[wv - 1];
        int carry = carry_s;
        int excl = carry + wbase + incl - v;
        if (i < NN) { offs[i] = excl; cursor[i] = excl; }
        __syncthreads();
        if (tid == 1023) carry_s = carry + wsum[15];
        __syncthreads();
    }
    if (threadIdx.x == 0) offs[NN] = carry_s;
}

__global__ __launch_bounds__(256) void fill_k(const void* __restrict__ eidx,
                                              const float* __restrict__ ew,
                                              const int* __restrict__ flag,
                                              int* __restrict__ cursor,
                                              int2* __restrict__ csr) {
    int e = blockIdx.x * 256 + threadIdx.x;
    if (e >= NE) return;
    int src, dst;
    if (*flag) {
        const long long* p = (const long long*)eidx;
        src = (int)p[e];
        dst = (int)p[NE + e];
    } else {
        const int* p = (const int*)eidx;
        src = p[e];
        dst = p[NE + e];
    }
    int pos = atomicAdd(&cursor[dst], 1);
    csr[pos] = make_int2(src, __float_as_int(ew[e]));
}

// ---------------------------------------------------------------------------
// Fused layer. 512-thread blocks, 8 waves, 4 NODES PER WAVE (32/block).
// - gather: 4 edge streams x depth-8 unroll = 32 row loads in flight/wave
// - MLP: one ds_read_b32 of W[k][lane] feeds 4 nodes' FMAs; h[k] broadcast
//   via v_readlane (VALU) instead of __shfl (ds_bpermute, LDS pipe).
//   LDS-pipe cost/node drops ~8x vs round 2.
// ---------------------------------------------------------------------------
__global__ __launch_bounds__(512) void layer_k(const float* __restrict__ xin,
                                               const float* __restrict__ Wl,
                                               const float* __restrict__ bl,
                                               const int* __restrict__ offs,
                                               const int2* __restrict__ csr,
                                               float* __restrict__ xout) {
    __shared__ float Ws[128 * 64];
    int tid = threadIdx.x;
    const float4* Wv = (const float4*)Wl;
    float4* Wsv = (float4*)Ws;
    #pragma unroll
    for (int i = 0; i < 4; ++i) Wsv[tid + 512 * i] = Wv[tid + 512 * i];
    __syncthreads();

    int wave = tid >> 6;
    int lane = tid & 63;
    int nbase = blockIdx.x * 32 + wave * 4;

    // clamped node ids (tail block): compute garbage for dups, mask stores
    int n0 = min(nbase + 0, NN - 1);
    int n1 = min(nbase + 1, NN - 1);
    int n2 = min(nbase + 2, NN - 1);
    int n3 = min(nbase + 3, NN - 1);

    // hoist own-row + bias
    float xl0 = xin[(size_t)n0 * DD + lane];
    float xl1 = xin[(size_t)n1 * DD + lane];
    float xl2 = xin[(size_t)n2 * DD + lane];
    float xl3 = xin[(size_t)n3 * DD + lane];
    float bias = bl[lane];

    int a0 = offs[n0], a1 = offs[n0 + 1];
    int b0 = offs[n1], b1 = offs[n1 + 1];
    int c0 = offs[n2], c1 = offs[n2 + 1];
    int d0 = offs[n3], d1 = offs[n3 + 1];
    int mx = max(max(a1 - a0, b1 - b0), max(c1 - c0, d1 - d0));

    float acc0 = 0.f, acc1 = 0.f, acc2 = 0.f, acc3 = 0.f;
    for (int base = 0; base < mx; base += 8) {
        float w0[8], v0[8], w1[8], v1[8], w2[8], v2[8], w3[8], v3[8];
        #pragma unroll
        for (int j = 0; j < 8; ++j) {
            int e;
            int2 sw;
            e = a0 + base + j;
            sw = csr[(e < a1) ? e : 0];
            w0[j] = (e < a1) ? __int_as_float(sw.y) : 0.f;
            v0[j] = xin[(size_t)sw.x * DD + lane];
            e = b0 + base + j;
            sw = csr[(e < b1) ? e : 0];
            w1[j] = (e < b1) ? __int_as_float(sw.y) : 0.f;
            v1[j] = xin[(size_t)sw.x * DD + lane];
            e = c0 + base + j;
            sw = csr[(e < c1) ? e : 0];
            w2[j] = (e < c1) ? __int_as_float(sw.y) : 0.f;
            v2[j] = xin[(size_t)sw.x * DD + lane];
            e = d0 + base + j;
            sw = csr[(e < d1) ? e : 0];
            w3[j] = (e < d1) ? __int_as_float(sw.y) : 0.f;
            v3[j] = xin[(size_t)sw.x * DD + lane];
        }
        #pragma unroll
        for (int j = 0; j < 8; ++j) {
            acc0 += w0[j] * v0[j];
            acc1 += w1[j] * v1[j];
            acc2 += w2[j] * v2[j];
            acc3 += w3[j] * v3[j];
        }
    }

    // l2norm of aggr (4 independent wave reductions)
    float s0 = acc0 * acc0, s1 = acc1 * acc1, s2 = acc2 * acc2, s3 = acc3 * acc3;
    #pragma unroll
    for (int off = 32; off > 0; off >>= 1) {
        s0 += __shfl_xor(s0, off);
        s1 += __shfl_xor(s1, off);
        s2 += __shfl_xor(s2, off);
        s3 += __shfl_xor(s3, off);
    }
    float an0 = acc0 / fmaxf(sqrtf(s0), 1e-12f);
    float an1 = acc1 / fmaxf(sqrtf(s1), 1e-12f);
    float an2 = acc2 / fmaxf(sqrtf(s2), 1e-12f);
    float an3 = acc3 / fmaxf(sqrtf(s3), 1e-12f);

    float o0 = bias, o1 = bias, o2 = bias, o3 = bias;
    #pragma unroll
    for (int k = 0; k < 64; ++k) {
        float wk = Ws[k * 64 + lane];
        o0 += rl(an0, k) * wk;
        o1 += rl(an1, k) * wk;
        o2 += rl(an2, k) * wk;
        o3 += rl(an3, k) * wk;
    }
    #pragma unroll
    for (int k = 0; k < 64; ++k) {
        float wk = Ws[(64 + k) * 64 + lane];
        o0 += rl(xl0, k) * wk;
        o1 += rl(xl1, k) * wk;
        o2 += rl(xl2, k) * wk;
        o3 += rl(xl3, k) * wk;
    }

    float q0 = o0 * o0, q1 = o1 * o1, q2 = o2 * o2, q3 = o3 * o3;
    #pragma unroll
    for (int off = 32; off > 0; off >>= 1) {
        q0 += __shfl_xor(q0, off);
        q1 += __shfl_xor(q1, off);
        q2 += __shfl_xor(q2, off);
        q3 += __shfl_xor(q3, off);
    }
    o0 /= fmaxf(sqrtf(q0), 1e-12f);
    o1 /= fmaxf(sqrtf(q1), 1e-12f);
    o2 /= fmaxf(sqrtf(q2), 1e-12f);
    o3 /= fmaxf(sqrtf(q3), 1e-12f);

    if (nbase + 0 < NN) xout[(size_t)(nbase + 0) * DD + lane] = o0;
    if (nbase + 1 < NN) xout[(size_t)(nbase + 1) * DD + lane] = o1;
    if (nbase + 2 < NN) xout[(size_t)(nbase + 2) * DD + lane] = o2;
    if (nbase + 3 < NN) xout[(size_t)(nbase + 3) * DD + lane] = o3;
}

// ---------------------------------------------------------------------------
extern "C" void kernel_launch(void* const* d_in, const int* in_sizes, int n_in,
                              void* d_out, int out_size, void* d_ws, size_t ws_size,
                              hipStream_t stream) {
    const float* x0  = (const float*)d_in[0];
    const void*  eidx = d_in[1];
    const float* ew  = (const float*)d_in[2];
    const float* W   = (const float*)d_in[3];
    const float* b   = (const float*)d_in[4];
    float* out = (float*)d_out;

    char* p = (char*)d_ws;
    auto alloc = [&](size_t bytes) {
        char* r = p;
        p += (bytes + 255) & ~(size_t)255;
        return r;
    };
    int*   flag   = (int*)alloc(4);
    int*   cnt    = (int*)alloc((size_t)NN * 4);
    int*   offs   = (int*)alloc((size_t)(NN + 1) * 4);
    int*   cursor = (int*)alloc((size_t)NN * 4);
    int2*  csr    = (int2*)alloc((size_t)NE * 8);
    float* bufA   = (float*)alloc((size_t)NN * DD * 4);

    hipMemsetAsync(cnt, 0, (size_t)NN * 4, stream);
    detect_i64<<<1, 256, 0, stream>>>((const unsigned int*)eidx, flag);
    hist_k<<<(NE + 255) / 256, 256, 0, stream>>>(eidx, flag, cnt);
    scan_k<<<1, 1024, 0, stream>>>(cnt, offs, cursor);
    fill_k<<<(NE + 255) / 256, 256, 0, stream>>>(eidx, ew, flag, cursor, csr);

    int nblk = (NN + 31) / 32;
    for (int i = 0; i < NL; ++i) {
        const float* xin = (i == 0) ? x0 : ((i % 2 == 1) ? bufA : out);
        float* xout = (i % 2 == 0) ? bufA : out;
        layer_k<<<nblk, 512, 0, stream>>>(xin, W + (size_t)i * 128 * 64,
                                          b + (size_t)i * 64, offs, csr, xout);
    }
}